// Round 22
// baseline (579.793 us; speedup 1.0000x reference)
//
#include <hip/hip_runtime.h>
#include <math.h>

#define B_    2048
#define LC    20
#define LQ    50
#define CTX   2048
#define CTXM  512
#define NEGV  -1e30f

typedef __fp16 half8 __attribute__((ext_vector_type(8)));
typedef __fp16 f16x2 __attribute__((ext_vector_type(2)));
typedef float f32x4  __attribute__((ext_vector_type(4)));
typedef unsigned int uint;

// ---------------- helpers: fp32 -> fp16 conversions ----------------
__device__ __forceinline__ half8 cvt8v(float4 a, float4 b) {
    union { f16x2 h[4]; half8 v; } r;
    r.h[0] = __builtin_amdgcn_cvt_pkrtz(a.x, a.y);
    r.h[1] = __builtin_amdgcn_cvt_pkrtz(a.z, a.w);
    r.h[2] = __builtin_amdgcn_cvt_pkrtz(b.x, b.y);
    r.h[3] = __builtin_amdgcn_cvt_pkrtz(b.z, b.w);
    return r.v;
}
__device__ __forceinline__ half8 cvt8(const float* x) {
    union { f16x2 h[4]; half8 v; } r;
    r.h[0] = __builtin_amdgcn_cvt_pkrtz(x[0], x[1]);
    r.h[1] = __builtin_amdgcn_cvt_pkrtz(x[2], x[3]);
    r.h[2] = __builtin_amdgcn_cvt_pkrtz(x[4], x[5]);
    r.h[3] = __builtin_amdgcn_cvt_pkrtz(x[6], x[7]);
    return r.v;
}

#define GLOAD_LDS16(g, l)                                                        \
    __builtin_amdgcn_global_load_lds(                                            \
        (const __attribute__((address_space(1))) unsigned int*)(g),              \
        (__attribute__((address_space(3))) unsigned int*)(l), 16, 0, 0)

// ---------------- Kernel 1: per-row scale = g[m] / ||trans_v[m,:]|| ----------------
__global__ __launch_bounds__(256)
void scale_kernel(const float* __restrict__ trans_v,
                  const float* __restrict__ trans_g,
                  float* __restrict__ scale) {
    int m = blockIdx.x;
    int t = threadIdx.x;
    const float* row = trans_v + (size_t)m * CTX;
    float ss = 0.f;
    for (int i = t; i < CTX; i += 256) { float v = row[i]; ss += v * v; }
    __shared__ float red[256];
    red[t] = ss;
    __syncthreads();
    for (int s = 128; s > 0; s >>= 1) {
        if (t < s) red[t] += red[t + s];
        __syncthreads();
    }
    if (t == 0) scale[m] = trans_g[m] / sqrtf(red[0]);
}

// ---------------- Kernel 1b: pack B = scale*Wt as SINGLE fp16, pre-swizzled tile order ----
__global__ __launch_bounds__(256)
void bpack_kernel(const float* __restrict__ Wt,
                  const float* __restrict__ scale,
                  char* __restrict__ Bp) {
    int u = blockIdx.x * 256 + threadIdx.x;     // one 16B unit, 131072 total
    int o = u * 16;
    int nslab  = o >> 20;
    int rem    = o & 1048575;
    int kchunk = rem >> 14;
    int rem2   = rem & 16383;
    int rpair  = rem2 >> 7;
    int cphys  = rem2 & 127;
    int clog   = cphys ^ ((rpair & 7) << 4);
    int rsub   = clog >> 6;
    int k0     = kchunk * 32 + ((clog & 63) >> 1);
    int n      = nslab * 256 + rpair * 2 + rsub;
    float s = scale[n];
    const float* wr = Wt + (size_t)n * CTX + k0;
    union { __fp16 h[8]; uint4 u4; } out;
#pragma unroll
    for (int e = 0; e < 8; e++) out.h[e] = (__fp16)(wr[e] * s);
    *(uint4*)&Bp[o] = out.u4;
}

// ---------------- Kernel 2: fp16 GEMM, counted-vmcnt pipeline (exact R18) ----------------
__global__ __launch_bounds__(512, 4)
void gemm_kernel(const float* __restrict__ A,        // (40960, 2048) fp32
                 const char*  __restrict__ Bp,       // packed pre-swizzled (2 MB)
                 const float* __restrict__ trans_b,  // (512)
                 float* __restrict__ V)              // (40960, 512)
{
    // LDS: [0,32768): B dbuf 2x16KB ([rpair 128][128B], XOR ((rp&7)<<4))
    //      [32768,49152): A dbuf 2x8KB ([slice 4][row 128][16B])
    __shared__ char lds[49152] __attribute__((aligned(16)));

    int t = threadIdx.x;
    int orig = blockIdx.x;
    int wg = (orig & 7) * 80 + (orig >> 3);     // bijective XCD swizzle (640 % 8 == 0)
    int nslab = wg & 1;
    int m0 = (wg >> 1) * 128;
    int n0 = nslab << 8;

    int wid = t >> 6, lane = t & 63;
    int l15 = lane & 15;
    int q16 = (lane >> 4) << 4;
    int ksl = lane >> 4;
    int rq  = (lane >> 4) << 2;
    int wm = (wid >> 2) << 6;
    int wn = (wid & 3) << 6;

    int r_a = t >> 2;
    int sl  = t & 3;
    int a_dst = 32768 + sl * 2048 + r_a * 16;
    const float* arow = A + (size_t)(m0 + r_a) * CTX + sl * 8;

    const char* bslab = Bp + (size_t)nslab * (64 * 16384);

    f32x4 acc[4][4];
#pragma unroll
    for (int i = 0; i < 4; i++)
#pragma unroll
        for (int j = 0; j < 4; j++) acc[i][j] = (f32x4){0.f, 0.f, 0.f, 0.f};

    // prologue: B(0) gloads first, then A(0), A(1) reg loads
    {
        const char* src = bslab + t * 16;
        GLOAD_LDS16(src, lds + t * 16);
        GLOAD_LDS16(src + 8192, lds + 8192 + t * 16);
    }
    float4 rAe0 = *(const float4*)(arow);
    float4 rAe1 = *(const float4*)(arow + 4);
    float4 rAo0 = *(const float4*)(arow + 32);
    float4 rAo1 = *(const float4*)(arow + 36);

    for (int ii = 0; ii < 32; ++ii) {
        int t0 = ii * 2;
        // ================= even phase (iter t0, buffers 0) =================
        *(half8*)&lds[a_dst] = cvt8v(rAe0, rAe1);
        asm volatile("s_waitcnt vmcnt(2)" ::: "memory");   // B(t0) landed; A prefetch flies
        asm volatile("s_waitcnt lgkmcnt(0)" ::: "memory"); // my A write visible
        __builtin_amdgcn_sched_barrier(0);
        __builtin_amdgcn_s_barrier();
        __builtin_amdgcn_sched_barrier(0);
        {   // issue B(t0+1) -> buf1
            const char* src = bslab + (size_t)(t0 + 1) * 16384 + t * 16;
            GLOAD_LDS16(src, lds + 16384 + t * 16);
            GLOAD_LDS16(src + 8192, lds + 16384 + 8192 + t * 16);
        }
        if (ii < 31) {   // issue A(t0+2) reg loads
            rAe0 = *(const float4*)(arow + (size_t)(t0 + 2) * 32);
            rAe1 = *(const float4*)(arow + (size_t)(t0 + 2) * 32 + 4);
        }
        {   // MFMA on buffers 0
            const char* Bb = lds;
            const char* Ab = lds + 32768;
            half8 af[4];
#pragma unroll
            for (int mt = 0; mt < 4; mt++)
                af[mt] = *(const half8*)&Ab[ksl * 2048 + (wm + mt * 16 + l15) * 16];
#pragma unroll
            for (int nt = 0; nt < 4; nt++) {
                int r  = wn + nt * 16 + l15;
                int rp = r >> 1;
                int c  = (r & 1) * 64 + q16;
                half8 bh = *(const half8*)&Bb[rp * 128 + (c ^ ((rp & 7) << 4))];
#pragma unroll
                for (int mt = 0; mt < 4; mt++)
                    acc[mt][nt] = __builtin_amdgcn_mfma_f32_16x16x32_f16(af[mt], bh, acc[mt][nt], 0, 0, 0);
            }
        }
        // ================= odd phase (iter t0+1, buffers 1) =================
        *(half8*)&lds[a_dst + 8192] = cvt8v(rAo0, rAo1);
        if (ii < 31) asm volatile("s_waitcnt vmcnt(2)" ::: "memory");
        else         asm volatile("s_waitcnt vmcnt(0)" ::: "memory");
        asm volatile("s_waitcnt lgkmcnt(0)" ::: "memory");
        __builtin_amdgcn_sched_barrier(0);
        __builtin_amdgcn_s_barrier();
        __builtin_amdgcn_sched_barrier(0);
        if (ii < 31) {
            {   // issue B(t0+2) -> buf0
                const char* src = bslab + (size_t)(t0 + 2) * 16384 + t * 16;
                GLOAD_LDS16(src, lds + t * 16);
                GLOAD_LDS16(src + 8192, lds + 8192 + t * 16);
            }
            rAo0 = *(const float4*)(arow + (size_t)(t0 + 3) * 32);
            rAo1 = *(const float4*)(arow + (size_t)(t0 + 3) * 32 + 4);
        }
        {   // MFMA on buffers 1
            const char* Bb = lds + 16384;
            const char* Ab = lds + 32768 + 8192;
            half8 af[4];
#pragma unroll
            for (int mt = 0; mt < 4; mt++)
                af[mt] = *(const half8*)&Ab[ksl * 2048 + (wm + mt * 16 + l15) * 16];
#pragma unroll
            for (int nt = 0; nt < 4; nt++) {
                int r  = wn + nt * 16 + l15;
                int rp = r >> 1;
                int c  = (r & 1) * 64 + q16;
                half8 bh = *(const half8*)&Bb[rp * 128 + (c ^ ((rp & 7) << 4))];
#pragma unroll
                for (int mt = 0; mt < 4; mt++)
                    acc[mt][nt] = __builtin_amdgcn_mfma_f32_16x16x32_f16(af[mt], bh, acc[mt][nt], 0, 0, 0);
            }
        }
    }

    // epilogue: +trans_b, store
#pragma unroll
    for (int nt = 0; nt < 4; nt++) {
        int col = n0 + wn + nt * 16 + l15;
        float tb = trans_b[col];
#pragma unroll
        for (int mt = 0; mt < 4; mt++) {
            int m = m0 + wm + mt * 16 + rq;
#pragma unroll
            for (int rg = 0; rg < 4; rg++)
                V[(size_t)(m + rg) * CTXM + col] = acc[mt][nt][rg] + tb;
        }
    }
}

// ---------------- Kernel 3: MFMA attention (R18 + nontemporal output stores) ----------------
__global__ __launch_bounds__(512, 2)
void attn_kernel(const float* __restrict__ Ques,    // (B, 512, 50)
                 const float* __restrict__ V_mask,  // (B, 20)
                 const float* __restrict__ Q_mask,  // (B, 50)
                 const float* __restrict__ w4V,     // (512)
                 const float* __restrict__ w4Q,     // (512)
                 const float* __restrict__ w4mlu,   // (512)
                 const float* __restrict__ bias,    // (1)
                 const float* __restrict__ V,       // (B*20, 512)
                 float* __restrict__ out)           // (B, 2048, 20)
{
    __shared__ __fp16 Qs[512 * 56 + 8];
    __shared__ float Ssh[LC][LQ];
    __shared__ float S1f[LC][LQ];
    __shared__ float S2f[LC][LQ];
    __shared__ __fp16 S1h[LC][72];
    __shared__ __fp16 S1l[LC][72];
    __shared__ __fp16 Bth[LC][40];
    __shared__ __fp16 Btl[LC][40];
    __shared__ float s1p[8][LQ];
    __shared__ float s0sh[LC];
    __shared__ float s1qsh[LQ];
    __shared__ float qmsh[LQ];
    __shared__ float vmsh[LC];

    int b = blockIdx.x;
    int t = threadIdx.x;
    int wid = t >> 6, lane = t & 63;
    int l15 = lane & 15;
    int kq  = (lane >> 4) << 3;
    int rq  = (lane >> 4) << 2;
    const float* Qb = Ques + (size_t)b * (CTXM * LQ);
    const float* Vb = V + (size_t)b * (LC * CTXM);

    if (t < LQ) qmsh[t] = Q_mask[(size_t)b * LQ + t];
    else if (t >= 64 && t < 64 + LC) vmsh[t - 64] = V_mask[(size_t)b * LC + (t - 64)];
    if (t < 8) Qs[512 * 56 + t] = (__fp16)0;

#pragma unroll
    for (int i = 0; i < 7; i++) {
        int task = t + 512 * i;
        int d  = task / 7;
        int sc = task - d * 7;
        const float* qr = Qb + (size_t)d * LQ + sc * 8;
        float xs[8];
        if (sc < 6) {
            float2 p0 = *(const float2*)&qr[0];
            float2 p1 = *(const float2*)&qr[2];
            float2 p2 = *(const float2*)&qr[4];
            float2 p3 = *(const float2*)&qr[6];
            xs[0] = p0.x; xs[1] = p0.y; xs[2] = p1.x; xs[3] = p1.y;
            xs[4] = p2.x; xs[5] = p2.y; xs[6] = p3.x; xs[7] = p3.y;
        } else {
            float2 p0 = *(const float2*)&qr[0];
            xs[0] = p0.x; xs[1] = p0.y;
            xs[2] = 0.f; xs[3] = 0.f; xs[4] = 0.f; xs[5] = 0.f;
            xs[6] = 0.f; xs[7] = 0.f;
        }
        *(half8*)&Qs[d * 56 + sc * 8] = cvt8(xs);
    }

    for (int l = wid; l < LC; l += 8) {
        float a = 0.f;
        const float* vr = Vb + (size_t)l * CTXM;
#pragma unroll
        for (int i = 0; i < CTXM / 64; i++)
            a = fmaf(vr[lane + 64 * i], w4V[lane + 64 * i], a);
#pragma unroll
        for (int o = 32; o > 0; o >>= 1) a += __shfl_xor(a, o);
        if (lane == 0) s0sh[l] = a;
    }
    __syncthreads();   // BAR1

    {
        int q = (lane < LQ) ? lane : (LQ - 1);
        float a = 0.f;
#pragma unroll
        for (int i = 0; i < 64; i++) {
            int d = (wid << 6) + i;
            a = fmaf((float)Qs[d * 56 + q], w4Q[d], a);
        }
        if (lane < LQ) s1p[wid][lane] = a;
    }

    int mt = wid >> 2, nt = wid & 3;
    f32x4 accS = {0.f, 0.f, 0.f, 0.f};
    {
        int lA = mt * 16 + l15; if (lA > LC - 1) lA = LC - 1;
        int qB = nt * 16 + l15; if (qB > LQ - 1) qB = LQ - 1;
        const float* vrow = Vb + (size_t)lA * CTXM;
        for (int kt = 0; kt < 16; kt++) {
            int d0 = kt * 32 + kq;
            float xa[8];
            float4 va = *(const float4*)&vrow[d0];
            float4 vc = *(const float4*)&vrow[d0 + 4];
            float4 wa = *(const float4*)&w4mlu[d0];
            float4 wc = *(const float4*)&w4mlu[d0 + 4];
            xa[0] = va.x * wa.x; xa[1] = va.y * wa.y; xa[2] = va.z * wa.z; xa[3] = va.w * wa.w;
            xa[4] = vc.x * wc.x; xa[5] = vc.y * wc.y; xa[6] = vc.z * wc.z; xa[7] = vc.w * wc.w;
            half8 vf = cvt8(xa);
            union { __fp16 h[8]; half8 v; } qq;
#pragma unroll
            for (int e = 0; e < 8; e++) qq.h[e] = Qs[(d0 + e) * 56 + qB];
            accS = __builtin_amdgcn_mfma_f32_16x16x32_f16(vf, qq.v, accS, 0, 0, 0);
        }
    }
    __syncthreads();   // BAR2

    if (t < LQ) {
        float s = 0.f;
#pragma unroll
        for (int w = 0; w < 8; w++) s += s1p[w][t];
        s1qsh[t] = s;
    }
    __syncthreads();   // BAR3

    {
        float bb = bias[0];
        int q = nt * 16 + l15;
#pragma unroll
        for (int r = 0; r < 4; r++) {
            int l = mt * 16 + rq + r;
            if (l < LC && q < LQ)
                Ssh[l][q] = accS[r] + s0sh[l] + s1qsh[q] + bb;
        }
    }
    __syncthreads();   // BAR4

    for (int l = wid; l < LC; l += 8) {
        float x;
        if (lane < LQ) {
            float qm = qmsh[lane];
            x = Ssh[l][lane] * qm + (1.f - qm) * NEGV;
        } else x = -INFINITY;
        float mx = x;
#pragma unroll
        for (int o = 32; o > 0; o >>= 1) mx = fmaxf(mx, __shfl_xor(mx, o));
        float e = (lane < LQ) ? expf(x - mx) : 0.f;
        float sum = e;
#pragma unroll
        for (int o = 32; o > 0; o >>= 1) sum += __shfl_xor(sum, o);
        float p = e / sum;
        if (lane < LQ) S1f[l][lane] = p;
        __fp16 hs = (__fp16)p;
        __fp16 ls = (__fp16)(p - (float)hs);
        S1h[l][lane] = (lane < LQ) ? hs : (__fp16)0;
        S1l[l][lane] = (lane < LQ) ? ls : (__fp16)0;
    }

    for (int ci = 0; ci < 7; ci++) {
        int c = wid * 7 + ci;
        if (c < LQ) {
            float x;
            if (lane < LC) {
                float vm = vmsh[lane];
                x = Ssh[lane][c] * vm + (1.f - vm) * NEGV;
            } else x = -INFINITY;
            float mx = x;
#pragma unroll
            for (int o = 32; o > 0; o >>= 1) mx = fmaxf(mx, __shfl_xor(mx, o));
            float e = (lane < LC) ? expf(x - mx) : 0.f;
            float sum = e;
#pragma unroll
            for (int o = 32; o > 0; o >>= 1) sum += __shfl_xor(sum, o);
            if (lane < LC) S2f[lane][c] = e / sum;
        }
    }
    __syncthreads();   // BAR5

    if (t < LC * LC) {
        int l = t % LC, m = t / LC;
        float s = 0.f;
#pragma unroll
        for (int j = 0; j < LQ; j++) s = fmaf(S1f[l][j], S2f[m][j], s);
        __fp16 hs = (__fp16)s;
        Bth[l][m] = hs;
        Btl[l][m] = (__fp16)(s - (float)hs);
    }
    if (t < 240) {
        int l = t % LC, m = LC + t / LC;
        Bth[l][m] = (__fp16)0; Btl[l][m] = (__fp16)0;
    }
    __syncthreads();   // BAR6

    float* outb = out + (size_t)b * (4 * CTXM * LC);
#pragma unroll 1
    for (int i = 0; i < 4; i++) {
        int dt = wid + 8 * i;
        int d0 = dt * 16;
        int dq = d0 + l15;
        half8 qf0 = *(const half8*)&Qs[dq * 56 + kq];
        half8 qf1 = *(const half8*)&Qs[dq * 56 + 32 + kq];
        float xv[8];
#pragma unroll
        for (int e = 0; e < 8; e++) {
            int m = kq + e;
            int mc = (m < LC) ? m : 0;
            float vv = Vb[(size_t)mc * CTXM + d0 + l15];
            xv[e] = (m < LC) ? vv : 0.f;
        }
        half8 vt = cvt8(xv);

        f32x4 accA[2] = {{0.f,0.f,0.f,0.f},{0.f,0.f,0.f,0.f}};
        f32x4 accB[2] = {{0.f,0.f,0.f,0.f},{0.f,0.f,0.f,0.f}};
#pragma unroll
        for (int n2 = 0; n2 < 2; n2++) {
            int lS = n2 * 16 + l15; if (lS > LC - 1) lS = LC - 1;
            half8 s1h0 = *(const half8*)&S1h[lS][kq];
            half8 s1l0 = *(const half8*)&S1l[lS][kq];
            half8 s1h1 = *(const half8*)&S1h[lS][32 + kq];
            half8 s1l1 = *(const half8*)&S1l[lS][32 + kq];
            accA[n2] = __builtin_amdgcn_mfma_f32_16x16x32_f16(qf0, s1h0, accA[n2], 0, 0, 0);
            accA[n2] = __builtin_amdgcn_mfma_f32_16x16x32_f16(qf0, s1l0, accA[n2], 0, 0, 0);
            accA[n2] = __builtin_amdgcn_mfma_f32_16x16x32_f16(qf1, s1h1, accA[n2], 0, 0, 0);
            accA[n2] = __builtin_amdgcn_mfma_f32_16x16x32_f16(qf1, s1l1, accA[n2], 0, 0, 0);
            half8 bh = *(const half8*)&Bth[lS][kq];
            half8 bl = *(const half8*)&Btl[lS][kq];
            accB[n2] = __builtin_amdgcn_mfma_f32_16x16x32_f16(vt, bh, accB[n2], 0, 0, 0);
            accB[n2] = __builtin_amdgcn_mfma_f32_16x16x32_f16(vt, bl, accB[n2], 0, 0, 0);
        }

#pragma unroll
        for (int n2 = 0; n2 < 2; n2++) {
            int l = n2 * 16 + l15;
            if (l < LC) {
#pragma unroll
                for (int r = 0; r < 4; r++) {
                    int d = d0 + rq + r;
                    float vv = Vb[(size_t)l * CTXM + d];
                    float a  = accA[n2][r];
                    float bv = accB[n2][r];
                    size_t base = (size_t)d * LC + l;
                    __builtin_nontemporal_store(vv,      &outb[base]);
                    __builtin_nontemporal_store(a,       &outb[base + CTXM * LC]);
                    __builtin_nontemporal_store(vv * a,  &outb[base + 2 * CTXM * LC]);
                    __builtin_nontemporal_store(vv * bv, &outb[base + 3 * CTXM * LC]);
                }
            }
        }
    }
}

extern "C" void kernel_launch(void* const* d_in, const int* in_sizes, int n_in,
                              void* d_out, int out_size, void* d_ws, size_t ws_size,
                              hipStream_t stream) {
    const float* Vid   = (const float*)d_in[0];
    const float* Ques  = (const float*)d_in[1];
    const float* Vmask = (const float*)d_in[2];
    const float* Qmask = (const float*)d_in[3];
    const float* tv    = (const float*)d_in[4];
    const float* tg    = (const float*)d_in[5];
    const float* tb    = (const float*)d_in[6];
    const float* w4V   = (const float*)d_in[7];
    const float* w4Q   = (const float*)d_in[8];
    const float* w4mlu = (const float*)d_in[9];
    const float* bias  = (const float*)d_in[10];
    float* out = (float*)d_out;

    float* scale = (float*)d_ws;                         // 512 f
    float* V     = scale + 512;                          // 40960*512 f (84 MB)
    char*  Bp    = (char*)(V + (size_t)40960 * 512);     // 2 MB packed B (single term)

    scale_kernel<<<512, 256, 0, stream>>>(tv, tg, scale);
    bpack_kernel<<<512, 256, 0, stream>>>(tv, scale, Bp);
    gemm_kernel<<<640, 512, 0, stream>>>(Vid, Bp, tb, V);
    attn_kernel<<<B_, 512, 0, stream>>>(Ques, Vmask, Qmask, w4V, w4Q, w4mlu, bias, V, out);
}

// Round 23
// 392.306 us; speedup vs baseline: 1.4779x; 1.4779x over previous
//
#include <hip/hip_runtime.h>
#include <math.h>

#define B_    2048
#define LC    20
#define LQ    50
#define CTX   2048
#define CTXM  512
#define NEGV  -1e30f

typedef __fp16 half8 __attribute__((ext_vector_type(8)));
typedef __fp16 f16x2 __attribute__((ext_vector_type(2)));
typedef float f32x4  __attribute__((ext_vector_type(4)));
typedef unsigned int uint;

// ---------------- helpers: fp32 -> fp16 conversions ----------------
__device__ __forceinline__ half8 cvt8v(float4 a, float4 b) {
    union { f16x2 h[4]; half8 v; } r;
    r.h[0] = __builtin_amdgcn_cvt_pkrtz(a.x, a.y);
    r.h[1] = __builtin_amdgcn_cvt_pkrtz(a.z, a.w);
    r.h[2] = __builtin_amdgcn_cvt_pkrtz(b.x, b.y);
    r.h[3] = __builtin_amdgcn_cvt_pkrtz(b.z, b.w);
    return r.v;
}
__device__ __forceinline__ half8 cvt8(const float* x) {
    union { f16x2 h[4]; half8 v; } r;
    r.h[0] = __builtin_amdgcn_cvt_pkrtz(x[0], x[1]);
    r.h[1] = __builtin_amdgcn_cvt_pkrtz(x[2], x[3]);
    r.h[2] = __builtin_amdgcn_cvt_pkrtz(x[4], x[5]);
    r.h[3] = __builtin_amdgcn_cvt_pkrtz(x[6], x[7]);
    return r.v;
}

#define GLOAD_LDS16(g, l)                                                        \
    __builtin_amdgcn_global_load_lds(                                            \
        (const __attribute__((address_space(1))) unsigned int*)(g),              \
        (__attribute__((address_space(3))) unsigned int*)(l), 16, 0, 0)

// ---------------- Kernel 1: per-row scale = g[m] / ||trans_v[m,:]|| ----------------
__global__ __launch_bounds__(256)
void scale_kernel(const float* __restrict__ trans_v,
                  const float* __restrict__ trans_g,
                  float* __restrict__ scale) {
    int m = blockIdx.x;
    int t = threadIdx.x;
    const float* row = trans_v + (size_t)m * CTX;
    float ss = 0.f;
    for (int i = t; i < CTX; i += 256) { float v = row[i]; ss += v * v; }
    __shared__ float red[256];
    red[t] = ss;
    __syncthreads();
    for (int s = 128; s > 0; s >>= 1) {
        if (t < s) red[t] += red[t + s];
        __syncthreads();
    }
    if (t == 0) scale[m] = trans_g[m] / sqrtf(red[0]);
}

// ---------------- Kernel 1b: pack B = scale*Wt as SINGLE fp16, pre-swizzled tile order ----
__global__ __launch_bounds__(256)
void bpack_kernel(const float* __restrict__ Wt,
                  const float* __restrict__ scale,
                  char* __restrict__ Bp) {
    int u = blockIdx.x * 256 + threadIdx.x;     // one 16B unit, 131072 total
    int o = u * 16;
    int nslab  = o >> 20;
    int rem    = o & 1048575;
    int kchunk = rem >> 14;
    int rem2   = rem & 16383;
    int rpair  = rem2 >> 7;
    int cphys  = rem2 & 127;
    int clog   = cphys ^ ((rpair & 7) << 4);
    int rsub   = clog >> 6;
    int k0     = kchunk * 32 + ((clog & 63) >> 1);
    int n      = nslab * 256 + rpair * 2 + rsub;
    float s = scale[n];
    const float* wr = Wt + (size_t)n * CTX + k0;
    union { __fp16 h[8]; uint4 u4; } out;
#pragma unroll
    for (int e = 0; e < 8; e++) out.h[e] = (__fp16)(wr[e] * s);
    *(uint4*)&Bp[o] = out.u4;
}

// ---------------- Kernel 2: fp16 GEMM, counted-vmcnt pipeline (exact R18) ----------------
__global__ __launch_bounds__(512, 4)
void gemm_kernel(const float* __restrict__ A,        // (40960, 2048) fp32
                 const char*  __restrict__ Bp,       // packed pre-swizzled (2 MB)
                 const float* __restrict__ trans_b,  // (512)
                 float* __restrict__ V)              // (40960, 512)
{
    // LDS: [0,32768): B dbuf 2x16KB ([rpair 128][128B], XOR ((rp&7)<<4))
    //      [32768,49152): A dbuf 2x8KB ([slice 4][row 128][16B])
    __shared__ char lds[49152] __attribute__((aligned(16)));

    int t = threadIdx.x;
    int orig = blockIdx.x;
    int wg = (orig & 7) * 80 + (orig >> 3);     // bijective XCD swizzle (640 % 8 == 0)
    int nslab = wg & 1;
    int m0 = (wg >> 1) * 128;
    int n0 = nslab << 8;

    int wid = t >> 6, lane = t & 63;
    int l15 = lane & 15;
    int q16 = (lane >> 4) << 4;
    int ksl = lane >> 4;
    int rq  = (lane >> 4) << 2;
    int wm = (wid >> 2) << 6;
    int wn = (wid & 3) << 6;

    int r_a = t >> 2;
    int sl  = t & 3;
    int a_dst = 32768 + sl * 2048 + r_a * 16;
    const float* arow = A + (size_t)(m0 + r_a) * CTX + sl * 8;

    const char* bslab = Bp + (size_t)nslab * (64 * 16384);

    f32x4 acc[4][4];
#pragma unroll
    for (int i = 0; i < 4; i++)
#pragma unroll
        for (int j = 0; j < 4; j++) acc[i][j] = (f32x4){0.f, 0.f, 0.f, 0.f};

    // prologue: B(0) gloads first, then A(0), A(1) reg loads
    {
        const char* src = bslab + t * 16;
        GLOAD_LDS16(src, lds + t * 16);
        GLOAD_LDS16(src + 8192, lds + 8192 + t * 16);
    }
    float4 rAe0 = *(const float4*)(arow);
    float4 rAe1 = *(const float4*)(arow + 4);
    float4 rAo0 = *(const float4*)(arow + 32);
    float4 rAo1 = *(const float4*)(arow + 36);

    for (int ii = 0; ii < 32; ++ii) {
        int t0 = ii * 2;
        // ================= even phase (iter t0, buffers 0) =================
        *(half8*)&lds[a_dst] = cvt8v(rAe0, rAe1);
        asm volatile("s_waitcnt vmcnt(2)" ::: "memory");   // B(t0) landed; A prefetch flies
        asm volatile("s_waitcnt lgkmcnt(0)" ::: "memory"); // my A write visible
        __builtin_amdgcn_sched_barrier(0);
        __builtin_amdgcn_s_barrier();
        __builtin_amdgcn_sched_barrier(0);
        {   // issue B(t0+1) -> buf1
            const char* src = bslab + (size_t)(t0 + 1) * 16384 + t * 16;
            GLOAD_LDS16(src, lds + 16384 + t * 16);
            GLOAD_LDS16(src + 8192, lds + 16384 + 8192 + t * 16);
        }
        if (ii < 31) {   // issue A(t0+2) reg loads
            rAe0 = *(const float4*)(arow + (size_t)(t0 + 2) * 32);
            rAe1 = *(const float4*)(arow + (size_t)(t0 + 2) * 32 + 4);
        }
        {   // MFMA on buffers 0
            const char* Bb = lds;
            const char* Ab = lds + 32768;
            half8 af[4];
#pragma unroll
            for (int mt = 0; mt < 4; mt++)
                af[mt] = *(const half8*)&Ab[ksl * 2048 + (wm + mt * 16 + l15) * 16];
#pragma unroll
            for (int nt = 0; nt < 4; nt++) {
                int r  = wn + nt * 16 + l15;
                int rp = r >> 1;
                int c  = (r & 1) * 64 + q16;
                half8 bh = *(const half8*)&Bb[rp * 128 + (c ^ ((rp & 7) << 4))];
#pragma unroll
                for (int mt = 0; mt < 4; mt++)
                    acc[mt][nt] = __builtin_amdgcn_mfma_f32_16x16x32_f16(af[mt], bh, acc[mt][nt], 0, 0, 0);
            }
        }
        // ================= odd phase (iter t0+1, buffers 1) =================
        *(half8*)&lds[a_dst + 8192] = cvt8v(rAo0, rAo1);
        if (ii < 31) asm volatile("s_waitcnt vmcnt(2)" ::: "memory");
        else         asm volatile("s_waitcnt vmcnt(0)" ::: "memory");
        asm volatile("s_waitcnt lgkmcnt(0)" ::: "memory");
        __builtin_amdgcn_sched_barrier(0);
        __builtin_amdgcn_s_barrier();
        __builtin_amdgcn_sched_barrier(0);
        if (ii < 31) {
            {   // issue B(t0+2) -> buf0
                const char* src = bslab + (size_t)(t0 + 2) * 16384 + t * 16;
                GLOAD_LDS16(src, lds + t * 16);
                GLOAD_LDS16(src + 8192, lds + 8192 + t * 16);
            }
            rAo0 = *(const float4*)(arow + (size_t)(t0 + 3) * 32);
            rAo1 = *(const float4*)(arow + (size_t)(t0 + 3) * 32 + 4);
        }
        {   // MFMA on buffers 1
            const char* Bb = lds + 16384;
            const char* Ab = lds + 32768 + 8192;
            half8 af[4];
#pragma unroll
            for (int mt = 0; mt < 4; mt++)
                af[mt] = *(const half8*)&Ab[ksl * 2048 + (wm + mt * 16 + l15) * 16];
#pragma unroll
            for (int nt = 0; nt < 4; nt++) {
                int r  = wn + nt * 16 + l15;
                int rp = r >> 1;
                int c  = (r & 1) * 64 + q16;
                half8 bh = *(const half8*)&Bb[rp * 128 + (c ^ ((rp & 7) << 4))];
#pragma unroll
                for (int mt = 0; mt < 4; mt++)
                    acc[mt][nt] = __builtin_amdgcn_mfma_f32_16x16x32_f16(af[mt], bh, acc[mt][nt], 0, 0, 0);
            }
        }
    }

    // epilogue: +trans_b, store
#pragma unroll
    for (int nt = 0; nt < 4; nt++) {
        int col = n0 + wn + nt * 16 + l15;
        float tb = trans_b[col];
#pragma unroll
        for (int mt = 0; mt < 4; mt++) {
            int m = m0 + wm + mt * 16 + rq;
#pragma unroll
            for (int rg = 0; rg < 4; rg++)
                V[(size_t)(m + rg) * CTXM + col] = acc[mt][nt][rg] + tb;
        }
    }
}

// ---------------- Kernel 3: MFMA attention (R18 + s1 folded into s2 MFMA) ----------------
__global__ __launch_bounds__(512, 2)
void attn_kernel(const float* __restrict__ Ques,    // (B, 512, 50)
                 const float* __restrict__ V_mask,  // (B, 20)
                 const float* __restrict__ Q_mask,  // (B, 50)
                 const float* __restrict__ w4V,     // (512)
                 const float* __restrict__ w4Q,     // (512)
                 const float* __restrict__ w4mlu,   // (512)
                 const float* __restrict__ bias,    // (1)
                 const float* __restrict__ V,       // (B*20, 512)
                 float* __restrict__ out)           // (B, 2048, 20)
{
    __shared__ __fp16 Qs[512 * 56 + 8];
    __shared__ float Ssh[LC][LQ];
    __shared__ float S1f[LC][LQ];
    __shared__ float S2f[LC][LQ];
    __shared__ __fp16 S1h[LC][72];
    __shared__ __fp16 S1l[LC][72];
    __shared__ __fp16 Bth[LC][40];
    __shared__ __fp16 Btl[LC][40];
    __shared__ float s0sh[LC];
    __shared__ float s1qsh[LQ];
    __shared__ float qmsh[LQ];
    __shared__ float vmsh[LC];

    int b = blockIdx.x;
    int t = threadIdx.x;
    int wid = t >> 6, lane = t & 63;
    int l15 = lane & 15;
    int kq  = (lane >> 4) << 3;
    int rq  = (lane >> 4) << 2;
    const float* Qb = Ques + (size_t)b * (CTXM * LQ);
    const float* Vb = V + (size_t)b * (LC * CTXM);

    if (t < LQ) qmsh[t] = Q_mask[(size_t)b * LQ + t];
    else if (t >= 64 && t < 64 + LC) vmsh[t - 64] = V_mask[(size_t)b * LC + (t - 64)];
    if (t < 8) Qs[512 * 56 + t] = (__fp16)0;

#pragma unroll
    for (int i = 0; i < 7; i++) {
        int task = t + 512 * i;
        int d  = task / 7;
        int sc = task - d * 7;
        const float* qr = Qb + (size_t)d * LQ + sc * 8;
        float xs[8];
        if (sc < 6) {
            float2 p0 = *(const float2*)&qr[0];
            float2 p1 = *(const float2*)&qr[2];
            float2 p2 = *(const float2*)&qr[4];
            float2 p3 = *(const float2*)&qr[6];
            xs[0] = p0.x; xs[1] = p0.y; xs[2] = p1.x; xs[3] = p1.y;
            xs[4] = p2.x; xs[5] = p2.y; xs[6] = p3.x; xs[7] = p3.y;
        } else {
            float2 p0 = *(const float2*)&qr[0];
            xs[0] = p0.x; xs[1] = p0.y;
            xs[2] = 0.f; xs[3] = 0.f; xs[4] = 0.f; xs[5] = 0.f;
            xs[6] = 0.f; xs[7] = 0.f;
        }
        *(half8*)&Qs[d * 56 + sc * 8] = cvt8(xs);
    }

    for (int l = wid; l < LC; l += 8) {
        float a = 0.f;
        const float* vr = Vb + (size_t)l * CTXM;
#pragma unroll
        for (int i = 0; i < CTXM / 64; i++)
            a = fmaf(vr[lane + 64 * i], w4V[lane + 64 * i], a);
#pragma unroll
        for (int o = 32; o > 0; o >>= 1) a += __shfl_xor(a, o);
        if (lane == 0) s0sh[l] = a;
    }
    __syncthreads();   // BAR1: Qs staged, s0sh / masks ready

    // ---- s2 via fp16 MFMA, with s1 folded in as A-row 20 (= w4Q) ----
    int mt = wid >> 2, nt = wid & 3;
    f32x4 accS = {0.f, 0.f, 0.f, 0.f};
    {
        int lA = mt * 16 + l15; if (lA > LC - 1) lA = LC - 1;
        int qB = nt * 16 + l15; if (qB > LQ - 1) qB = LQ - 1;
        bool isW4Q = (mt == 1) && (l15 == 4);   // logical A-row 20
        const float* vrow = Vb + (size_t)lA * CTXM;
        for (int kt = 0; kt < 16; kt++) {
            int d0 = kt * 32 + kq;
            float xa[8];
            float4 va = *(const float4*)&vrow[d0];
            float4 vc = *(const float4*)&vrow[d0 + 4];
            float4 wa = *(const float4*)&w4mlu[d0];
            float4 wc = *(const float4*)&w4mlu[d0 + 4];
            xa[0] = va.x * wa.x; xa[1] = va.y * wa.y; xa[2] = va.z * wa.z; xa[3] = va.w * wa.w;
            xa[4] = vc.x * wc.x; xa[5] = vc.y * wc.y; xa[6] = vc.z * wc.z; xa[7] = vc.w * wc.w;
            if (mt == 1) {   // rows 16-31: row 20 carries w4Q
                float4 qa = *(const float4*)&w4Q[d0];
                float4 qc = *(const float4*)&w4Q[d0 + 4];
                if (isW4Q) {
                    xa[0] = qa.x; xa[1] = qa.y; xa[2] = qa.z; xa[3] = qa.w;
                    xa[4] = qc.x; xa[5] = qc.y; xa[6] = qc.z; xa[7] = qc.w;
                }
            }
            half8 vf = cvt8(xa);
            union { __fp16 h[8]; half8 v; } qq;
#pragma unroll
            for (int e = 0; e < 8; e++) qq.h[e] = Qs[(d0 + e) * 56 + qB];
            accS = __builtin_amdgcn_mfma_f32_16x16x32_f16(vf, qq.v, accS, 0, 0, 0);
        }
    }
    // C row = mt*16 + (lane>>4)*4 + r; row 20 => mt==1, lane>>4==1, r==0  -> s1[q]
    if (mt == 1 && (lane >> 4) == 1) {
        int qcol = nt * 16 + l15;
        if (qcol < LQ) s1qsh[qcol] = accS[0];
    }
    __syncthreads();   // BAR2: s1qsh ready

    {
        float bb = bias[0];
        int q = nt * 16 + l15;
#pragma unroll
        for (int r = 0; r < 4; r++) {
            int l = mt * 16 + rq + r;
            if (l < LC && q < LQ)
                Ssh[l][q] = accS[r] + s0sh[l] + s1qsh[q] + bb;
        }
    }
    __syncthreads();   // BAR3: Ssh ready

    for (int l = wid; l < LC; l += 8) {
        float x;
        if (lane < LQ) {
            float qm = qmsh[lane];
            x = Ssh[l][lane] * qm + (1.f - qm) * NEGV;
        } else x = -INFINITY;
        float mx = x;
#pragma unroll
        for (int o = 32; o > 0; o >>= 1) mx = fmaxf(mx, __shfl_xor(mx, o));
        float e = (lane < LQ) ? expf(x - mx) : 0.f;
        float sum = e;
#pragma unroll
        for (int o = 32; o > 0; o >>= 1) sum += __shfl_xor(sum, o);
        float p = e / sum;
        if (lane < LQ) S1f[l][lane] = p;
        __fp16 hs = (__fp16)p;
        __fp16 ls = (__fp16)(p - (float)hs);
        S1h[l][lane] = (lane < LQ) ? hs : (__fp16)0;
        S1l[l][lane] = (lane < LQ) ? ls : (__fp16)0;
    }

    for (int ci = 0; ci < 7; ci++) {
        int c = wid * 7 + ci;
        if (c < LQ) {
            float x;
            if (lane < LC) {
                float vm = vmsh[lane];
                x = Ssh[lane][c] * vm + (1.f - vm) * NEGV;
            } else x = -INFINITY;
            float mx = x;
#pragma unroll
            for (int o = 32; o > 0; o >>= 1) mx = fmaxf(mx, __shfl_xor(mx, o));
            float e = (lane < LC) ? expf(x - mx) : 0.f;
            float sum = e;
#pragma unroll
            for (int o = 32; o > 0; o >>= 1) sum += __shfl_xor(sum, o);
            if (lane < LC) S2f[lane][c] = e / sum;
        }
    }
    __syncthreads();   // BAR4

    if (t < LC * LC) {
        int l = t % LC, m = t / LC;
        float s = 0.f;
#pragma unroll
        for (int j = 0; j < LQ; j++) s = fmaf(S1f[l][j], S2f[m][j], s);
        __fp16 hs = (__fp16)s;
        Bth[l][m] = hs;
        Btl[l][m] = (__fp16)(s - (float)hs);
    }
    if (t < 240) {
        int l = t % LC, m = LC + t / LC;
        Bth[l][m] = (__fp16)0; Btl[l][m] = (__fp16)0;
    }
    __syncthreads();   // BAR5

    float* outb = out + (size_t)b * (4 * CTXM * LC);
#pragma unroll 1
    for (int i = 0; i < 4; i++) {
        int dt = wid + 8 * i;
        int d0 = dt * 16;
        int dq = d0 + l15;
        half8 qf0 = *(const half8*)&Qs[dq * 56 + kq];
        half8 qf1 = *(const half8*)&Qs[dq * 56 + 32 + kq];
        float xv[8];
#pragma unroll
        for (int e = 0; e < 8; e++) {
            int m = kq + e;
            int mc = (m < LC) ? m : 0;
            float vv = Vb[(size_t)mc * CTXM + d0 + l15];
            xv[e] = (m < LC) ? vv : 0.f;
        }
        half8 vt = cvt8(xv);

        f32x4 accA[2] = {{0.f,0.f,0.f,0.f},{0.f,0.f,0.f,0.f}};
        f32x4 accB[2] = {{0.f,0.f,0.f,0.f},{0.f,0.f,0.f,0.f}};
#pragma unroll
        for (int n2 = 0; n2 < 2; n2++) {
            int lS = n2 * 16 + l15; if (lS > LC - 1) lS = LC - 1;
            half8 s1h0 = *(const half8*)&S1h[lS][kq];
            half8 s1l0 = *(const half8*)&S1l[lS][kq];
            half8 s1h1 = *(const half8*)&S1h[lS][32 + kq];
            half8 s1l1 = *(const half8*)&S1l[lS][32 + kq];
            accA[n2] = __builtin_amdgcn_mfma_f32_16x16x32_f16(qf0, s1h0, accA[n2], 0, 0, 0);
            accA[n2] = __builtin_amdgcn_mfma_f32_16x16x32_f16(qf0, s1l0, accA[n2], 0, 0, 0);
            accA[n2] = __builtin_amdgcn_mfma_f32_16x16x32_f16(qf1, s1h1, accA[n2], 0, 0, 0);
            accA[n2] = __builtin_amdgcn_mfma_f32_16x16x32_f16(qf1, s1l1, accA[n2], 0, 0, 0);
            half8 bh = *(const half8*)&Bth[lS][kq];
            half8 bl = *(const half8*)&Btl[lS][kq];
            accB[n2] = __builtin_amdgcn_mfma_f32_16x16x32_f16(vt, bh, accB[n2], 0, 0, 0);
            accB[n2] = __builtin_amdgcn_mfma_f32_16x16x32_f16(vt, bl, accB[n2], 0, 0, 0);
        }

#pragma unroll
        for (int n2 = 0; n2 < 2; n2++) {
            int l = n2 * 16 + l15;
            if (l < LC) {
#pragma unroll
                for (int r = 0; r < 4; r++) {
                    int d = d0 + rq + r;
                    float vv = Vb[(size_t)l * CTXM + d];
                    float a  = accA[n2][r];
                    float bv = accB[n2][r];
                    size_t base = (size_t)d * LC + l;
                    outb[base]                 = vv;
                    outb[base + CTXM * LC]     = a;
                    outb[base + 2 * CTXM * LC] = vv * a;
                    outb[base + 3 * CTXM * LC] = vv * bv;
                }
            }
        }
    }
}

extern "C" void kernel_launch(void* const* d_in, const int* in_sizes, int n_in,
                              void* d_out, int out_size, void* d_ws, size_t ws_size,
                              hipStream_t stream) {
    const float* Vid   = (const float*)d_in[0];
    const float* Ques  = (const float*)d_in[1];
    const float* Vmask = (const float*)d_in[2];
    const float* Qmask = (const float*)d_in[3];
    const float* tv    = (const float*)d_in[4];
    const float* tg    = (const float*)d_in[5];
    const float* tb    = (const float*)d_in[6];
    const float* w4V   = (const float*)d_in[7];
    const float* w4Q   = (const float*)d_in[8];
    const float* w4mlu = (const float*)d_in[9];
    const float* bias  = (const float*)d_in[10];
    float* out = (float*)d_out;

    float* scale = (float*)d_ws;                         // 512 f
    float* V     = scale + 512;                          // 40960*512 f (84 MB)
    char*  Bp    = (char*)(V + (size_t)40960 * 512);     // 2 MB packed B (single term)

    scale_kernel<<<512, 256, 0, stream>>>(tv, tg, scale);
    bpack_kernel<<<512, 256, 0, stream>>>(tv, scale, Bp);
    gemm_kernel<<<640, 512, 0, stream>>>(Vid, Bp, tb, V);
    attn_kernel<<<B_, 512, 0, stream>>>(Ques, Vmask, Qmask, w4V, w4Q, w4mlu, bias, V, out);
}

// Round 24
// 368.820 us; speedup vs baseline: 1.5720x; 1.0637x over previous
//
#include <hip/hip_runtime.h>
#include <math.h>

#define B_    2048
#define LC    20
#define LQ    50
#define CTX   2048
#define CTXM  512
#define NEGV  -1e30f

typedef __fp16 half8 __attribute__((ext_vector_type(8)));
typedef __fp16 f16x2 __attribute__((ext_vector_type(2)));
typedef float f32x4  __attribute__((ext_vector_type(4)));
typedef unsigned int uint;

// ---------------- helpers: fp32 -> fp16 conversions ----------------
__device__ __forceinline__ half8 cvt8v(float4 a, float4 b) {
    union { f16x2 h[4]; half8 v; } r;
    r.h[0] = __builtin_amdgcn_cvt_pkrtz(a.x, a.y);
    r.h[1] = __builtin_amdgcn_cvt_pkrtz(a.z, a.w);
    r.h[2] = __builtin_amdgcn_cvt_pkrtz(b.x, b.y);
    r.h[3] = __builtin_amdgcn_cvt_pkrtz(b.z, b.w);
    return r.v;
}
__device__ __forceinline__ half8 cvt8(const float* x) {
    union { f16x2 h[4]; half8 v; } r;
    r.h[0] = __builtin_amdgcn_cvt_pkrtz(x[0], x[1]);
    r.h[1] = __builtin_amdgcn_cvt_pkrtz(x[2], x[3]);
    r.h[2] = __builtin_amdgcn_cvt_pkrtz(x[4], x[5]);
    r.h[3] = __builtin_amdgcn_cvt_pkrtz(x[6], x[7]);
    return r.v;
}

#define GLOAD_LDS16(g, l)                                                        \
    __builtin_amdgcn_global_load_lds(                                            \
        (const __attribute__((address_space(1))) unsigned int*)(g),              \
        (__attribute__((address_space(3))) unsigned int*)(l), 16, 0, 0)

// ---------------- Kernel 1: per-row scale = g[m] / ||trans_v[m,:]|| ----------------
__global__ __launch_bounds__(256)
void scale_kernel(const float* __restrict__ trans_v,
                  const float* __restrict__ trans_g,
                  float* __restrict__ scale) {
    int m = blockIdx.x;
    int t = threadIdx.x;
    const float* row = trans_v + (size_t)m * CTX;
    float ss = 0.f;
    for (int i = t; i < CTX; i += 256) { float v = row[i]; ss += v * v; }
    __shared__ float red[256];
    red[t] = ss;
    __syncthreads();
    for (int s = 128; s > 0; s >>= 1) {
        if (t < s) red[t] += red[t + s];
        __syncthreads();
    }
    if (t == 0) scale[m] = trans_g[m] / sqrtf(red[0]);
}

// ---------------- Kernel 1b: pack B = scale*Wt as SINGLE fp16, pre-swizzled tile order ----
__global__ __launch_bounds__(256)
void bpack_kernel(const float* __restrict__ Wt,
                  const float* __restrict__ scale,
                  char* __restrict__ Bp) {
    int u = blockIdx.x * 256 + threadIdx.x;     // one 16B unit, 131072 total
    int o = u * 16;
    int nslab  = o >> 20;
    int rem    = o & 1048575;
    int kchunk = rem >> 14;
    int rem2   = rem & 16383;
    int rpair  = rem2 >> 7;
    int cphys  = rem2 & 127;
    int clog   = cphys ^ ((rpair & 7) << 4);
    int rsub   = clog >> 6;
    int k0     = kchunk * 32 + ((clog & 63) >> 1);
    int n      = nslab * 256 + rpair * 2 + rsub;
    float s = scale[n];
    const float* wr = Wt + (size_t)n * CTX + k0;
    union { __fp16 h[8]; uint4 u4; } out;
#pragma unroll
    for (int e = 0; e < 8; e++) out.h[e] = (__fp16)(wr[e] * s);
    *(uint4*)&Bp[o] = out.u4;
}

// ---------------- Kernel 2: fp16 GEMM, counted-vmcnt pipeline (exact R18) ----------------
__global__ __launch_bounds__(512, 4)
void gemm_kernel(const float* __restrict__ A,        // (40960, 2048) fp32
                 const char*  __restrict__ Bp,       // packed pre-swizzled (2 MB)
                 const float* __restrict__ trans_b,  // (512)
                 float* __restrict__ V)              // (40960, 512)
{
    // LDS: [0,32768): B dbuf 2x16KB ([rpair 128][128B], XOR ((rp&7)<<4))
    //      [32768,49152): A dbuf 2x8KB ([slice 4][row 128][16B])
    __shared__ char lds[49152] __attribute__((aligned(16)));

    int t = threadIdx.x;
    int orig = blockIdx.x;
    int wg = (orig & 7) * 80 + (orig >> 3);     // bijective XCD swizzle (640 % 8 == 0)
    int nslab = wg & 1;
    int m0 = (wg >> 1) * 128;
    int n0 = nslab << 8;

    int wid = t >> 6, lane = t & 63;
    int l15 = lane & 15;
    int q16 = (lane >> 4) << 4;
    int ksl = lane >> 4;
    int rq  = (lane >> 4) << 2;
    int wm = (wid >> 2) << 6;
    int wn = (wid & 3) << 6;

    int r_a = t >> 2;
    int sl  = t & 3;
    int a_dst = 32768 + sl * 2048 + r_a * 16;
    const float* arow = A + (size_t)(m0 + r_a) * CTX + sl * 8;

    const char* bslab = Bp + (size_t)nslab * (64 * 16384);

    f32x4 acc[4][4];
#pragma unroll
    for (int i = 0; i < 4; i++)
#pragma unroll
        for (int j = 0; j < 4; j++) acc[i][j] = (f32x4){0.f, 0.f, 0.f, 0.f};

    // prologue: B(0) gloads first, then A(0), A(1) reg loads
    {
        const char* src = bslab + t * 16;
        GLOAD_LDS16(src, lds + t * 16);
        GLOAD_LDS16(src + 8192, lds + 8192 + t * 16);
    }
    float4 rAe0 = *(const float4*)(arow);
    float4 rAe1 = *(const float4*)(arow + 4);
    float4 rAo0 = *(const float4*)(arow + 32);
    float4 rAo1 = *(const float4*)(arow + 36);

    for (int ii = 0; ii < 32; ++ii) {
        int t0 = ii * 2;
        // ================= even phase (iter t0, buffers 0) =================
        *(half8*)&lds[a_dst] = cvt8v(rAe0, rAe1);
        asm volatile("s_waitcnt vmcnt(2)" ::: "memory");   // B(t0) landed; A prefetch flies
        asm volatile("s_waitcnt lgkmcnt(0)" ::: "memory"); // my A write visible
        __builtin_amdgcn_sched_barrier(0);
        __builtin_amdgcn_s_barrier();
        __builtin_amdgcn_sched_barrier(0);
        {   // issue B(t0+1) -> buf1
            const char* src = bslab + (size_t)(t0 + 1) * 16384 + t * 16;
            GLOAD_LDS16(src, lds + 16384 + t * 16);
            GLOAD_LDS16(src + 8192, lds + 16384 + 8192 + t * 16);
        }
        if (ii < 31) {   // issue A(t0+2) reg loads
            rAe0 = *(const float4*)(arow + (size_t)(t0 + 2) * 32);
            rAe1 = *(const float4*)(arow + (size_t)(t0 + 2) * 32 + 4);
        }
        {   // MFMA on buffers 0
            const char* Bb = lds;
            const char* Ab = lds + 32768;
            half8 af[4];
#pragma unroll
            for (int mt = 0; mt < 4; mt++)
                af[mt] = *(const half8*)&Ab[ksl * 2048 + (wm + mt * 16 + l15) * 16];
#pragma unroll
            for (int nt = 0; nt < 4; nt++) {
                int r  = wn + nt * 16 + l15;
                int rp = r >> 1;
                int c  = (r & 1) * 64 + q16;
                half8 bh = *(const half8*)&Bb[rp * 128 + (c ^ ((rp & 7) << 4))];
#pragma unroll
                for (int mt = 0; mt < 4; mt++)
                    acc[mt][nt] = __builtin_amdgcn_mfma_f32_16x16x32_f16(af[mt], bh, acc[mt][nt], 0, 0, 0);
            }
        }
        // ================= odd phase (iter t0+1, buffers 1) =================
        *(half8*)&lds[a_dst + 8192] = cvt8v(rAo0, rAo1);
        if (ii < 31) asm volatile("s_waitcnt vmcnt(2)" ::: "memory");
        else         asm volatile("s_waitcnt vmcnt(0)" ::: "memory");
        asm volatile("s_waitcnt lgkmcnt(0)" ::: "memory");
        __builtin_amdgcn_sched_barrier(0);
        __builtin_amdgcn_s_barrier();
        __builtin_amdgcn_sched_barrier(0);
        if (ii < 31) {
            {   // issue B(t0+2) -> buf0
                const char* src = bslab + (size_t)(t0 + 2) * 16384 + t * 16;
                GLOAD_LDS16(src, lds + t * 16);
                GLOAD_LDS16(src + 8192, lds + 8192 + t * 16);
            }
            rAo0 = *(const float4*)(arow + (size_t)(t0 + 3) * 32);
            rAo1 = *(const float4*)(arow + (size_t)(t0 + 3) * 32 + 4);
        }
        {   // MFMA on buffers 1
            const char* Bb = lds + 16384;
            const char* Ab = lds + 32768 + 8192;
            half8 af[4];
#pragma unroll
            for (int mt = 0; mt < 4; mt++)
                af[mt] = *(const half8*)&Ab[ksl * 2048 + (wm + mt * 16 + l15) * 16];
#pragma unroll
            for (int nt = 0; nt < 4; nt++) {
                int r  = wn + nt * 16 + l15;
                int rp = r >> 1;
                int c  = (r & 1) * 64 + q16;
                half8 bh = *(const half8*)&Bb[rp * 128 + (c ^ ((rp & 7) << 4))];
#pragma unroll
                for (int mt = 0; mt < 4; mt++)
                    acc[mt][nt] = __builtin_amdgcn_mfma_f32_16x16x32_f16(af[mt], bh, acc[mt][nt], 0, 0, 0);
            }
        }
    }

    // epilogue: +trans_b, store
#pragma unroll
    for (int nt = 0; nt < 4; nt++) {
        int col = n0 + wn + nt * 16 + l15;
        float tb = trans_b[col];
#pragma unroll
        for (int mt = 0; mt < 4; mt++) {
            int m = m0 + wm + mt * 16 + rq;
#pragma unroll
            for (int rg = 0; rg < 4; rg++)
                V[(size_t)(m + rg) * CTXM + col] = acc[mt][nt][rg] + tb;
        }
    }
}

// ---------------- Kernel 3: MFMA attention (exact R18) ----------------
__global__ __launch_bounds__(512, 2)
void attn_kernel(const float* __restrict__ Ques,    // (B, 512, 50)
                 const float* __restrict__ V_mask,  // (B, 20)
                 const float* __restrict__ Q_mask,  // (B, 50)
                 const float* __restrict__ w4V,     // (512)
                 const float* __restrict__ w4Q,     // (512)
                 const float* __restrict__ w4mlu,   // (512)
                 const float* __restrict__ bias,    // (1)
                 const float* __restrict__ V,       // (B*20, 512)
                 float* __restrict__ out)           // (B, 2048, 20)
{
    __shared__ __fp16 Qs[512 * 56 + 8];
    __shared__ float Ssh[LC][LQ];
    __shared__ float S1f[LC][LQ];
    __shared__ float S2f[LC][LQ];
    __shared__ __fp16 S1h[LC][72];
    __shared__ __fp16 S1l[LC][72];
    __shared__ __fp16 Bth[LC][40];
    __shared__ __fp16 Btl[LC][40];
    __shared__ float s1p[8][LQ];
    __shared__ float s0sh[LC];
    __shared__ float s1qsh[LQ];
    __shared__ float qmsh[LQ];
    __shared__ float vmsh[LC];

    int b = blockIdx.x;
    int t = threadIdx.x;
    int wid = t >> 6, lane = t & 63;
    int l15 = lane & 15;
    int kq  = (lane >> 4) << 3;
    int rq  = (lane >> 4) << 2;
    const float* Qb = Ques + (size_t)b * (CTXM * LQ);
    const float* Vb = V + (size_t)b * (LC * CTXM);

    if (t < LQ) qmsh[t] = Q_mask[(size_t)b * LQ + t];
    else if (t >= 64 && t < 64 + LC) vmsh[t - 64] = V_mask[(size_t)b * LC + (t - 64)];
    if (t < 8) Qs[512 * 56 + t] = (__fp16)0;

#pragma unroll
    for (int i = 0; i < 7; i++) {
        int task = t + 512 * i;
        int d  = task / 7;
        int sc = task - d * 7;
        const float* qr = Qb + (size_t)d * LQ + sc * 8;
        float xs[8];
        if (sc < 6) {
            float2 p0 = *(const float2*)&qr[0];
            float2 p1 = *(const float2*)&qr[2];
            float2 p2 = *(const float2*)&qr[4];
            float2 p3 = *(const float2*)&qr[6];
            xs[0] = p0.x; xs[1] = p0.y; xs[2] = p1.x; xs[3] = p1.y;
            xs[4] = p2.x; xs[5] = p2.y; xs[6] = p3.x; xs[7] = p3.y;
        } else {
            float2 p0 = *(const float2*)&qr[0];
            xs[0] = p0.x; xs[1] = p0.y;
            xs[2] = 0.f; xs[3] = 0.f; xs[4] = 0.f; xs[5] = 0.f;
            xs[6] = 0.f; xs[7] = 0.f;
        }
        *(half8*)&Qs[d * 56 + sc * 8] = cvt8(xs);
    }

    for (int l = wid; l < LC; l += 8) {
        float a = 0.f;
        const float* vr = Vb + (size_t)l * CTXM;
#pragma unroll
        for (int i = 0; i < CTXM / 64; i++)
            a = fmaf(vr[lane + 64 * i], w4V[lane + 64 * i], a);
#pragma unroll
        for (int o = 32; o > 0; o >>= 1) a += __shfl_xor(a, o);
        if (lane == 0) s0sh[l] = a;
    }
    __syncthreads();   // BAR1

    {
        int q = (lane < LQ) ? lane : (LQ - 1);
        float a = 0.f;
#pragma unroll
        for (int i = 0; i < 64; i++) {
            int d = (wid << 6) + i;
            a = fmaf((float)Qs[d * 56 + q], w4Q[d], a);
        }
        if (lane < LQ) s1p[wid][lane] = a;
    }

    int mt = wid >> 2, nt = wid & 3;
    f32x4 accS = {0.f, 0.f, 0.f, 0.f};
    {
        int lA = mt * 16 + l15; if (lA > LC - 1) lA = LC - 1;
        int qB = nt * 16 + l15; if (qB > LQ - 1) qB = LQ - 1;
        const float* vrow = Vb + (size_t)lA * CTXM;
        for (int kt = 0; kt < 16; kt++) {
            int d0 = kt * 32 + kq;
            float xa[8];
            float4 va = *(const float4*)&vrow[d0];
            float4 vc = *(const float4*)&vrow[d0 + 4];
            float4 wa = *(const float4*)&w4mlu[d0];
            float4 wc = *(const float4*)&w4mlu[d0 + 4];
            xa[0] = va.x * wa.x; xa[1] = va.y * wa.y; xa[2] = va.z * wa.z; xa[3] = va.w * wa.w;
            xa[4] = vc.x * wc.x; xa[5] = vc.y * wc.y; xa[6] = vc.z * wc.z; xa[7] = vc.w * wc.w;
            half8 vf = cvt8(xa);
            union { __fp16 h[8]; half8 v; } qq;
#pragma unroll
            for (int e = 0; e < 8; e++) qq.h[e] = Qs[(d0 + e) * 56 + qB];
            accS = __builtin_amdgcn_mfma_f32_16x16x32_f16(vf, qq.v, accS, 0, 0, 0);
        }
    }
    __syncthreads();   // BAR2

    if (t < LQ) {
        float s = 0.f;
#pragma unroll
        for (int w = 0; w < 8; w++) s += s1p[w][t];
        s1qsh[t] = s;
    }
    __syncthreads();   // BAR3

    {
        float bb = bias[0];
        int q = nt * 16 + l15;
#pragma unroll
        for (int r = 0; r < 4; r++) {
            int l = mt * 16 + rq + r;
            if (l < LC && q < LQ)
                Ssh[l][q] = accS[r] + s0sh[l] + s1qsh[q] + bb;
        }
    }
    __syncthreads();   // BAR4

    for (int l = wid; l < LC; l += 8) {
        float x;
        if (lane < LQ) {
            float qm = qmsh[lane];
            x = Ssh[l][lane] * qm + (1.f - qm) * NEGV;
        } else x = -INFINITY;
        float mx = x;
#pragma unroll
        for (int o = 32; o > 0; o >>= 1) mx = fmaxf(mx, __shfl_xor(mx, o));
        float e = (lane < LQ) ? expf(x - mx) : 0.f;
        float sum = e;
#pragma unroll
        for (int o = 32; o > 0; o >>= 1) sum += __shfl_xor(sum, o);
        float p = e / sum;
        if (lane < LQ) S1f[l][lane] = p;
        __fp16 hs = (__fp16)p;
        __fp16 ls = (__fp16)(p - (float)hs);
        S1h[l][lane] = (lane < LQ) ? hs : (__fp16)0;
        S1l[l][lane] = (lane < LQ) ? ls : (__fp16)0;
    }

    for (int ci = 0; ci < 7; ci++) {
        int c = wid * 7 + ci;
        if (c < LQ) {
            float x;
            if (lane < LC) {
                float vm = vmsh[lane];
                x = Ssh[lane][c] * vm + (1.f - vm) * NEGV;
            } else x = -INFINITY;
            float mx = x;
#pragma unroll
            for (int o = 32; o > 0; o >>= 1) mx = fmaxf(mx, __shfl_xor(mx, o));
            float e = (lane < LC) ? expf(x - mx) : 0.f;
            float sum = e;
#pragma unroll
            for (int o = 32; o > 0; o >>= 1) sum += __shfl_xor(sum, o);
            if (lane < LC) S2f[lane][c] = e / sum;
        }
    }
    __syncthreads();   // BAR5

    if (t < LC * LC) {
        int l = t % LC, m = t / LC;
        float s = 0.f;
#pragma unroll
        for (int j = 0; j < LQ; j++) s = fmaf(S1f[l][j], S2f[m][j], s);
        __fp16 hs = (__fp16)s;
        Bth[l][m] = hs;
        Btl[l][m] = (__fp16)(s - (float)hs);
    }
    if (t < 240) {
        int l = t % LC, m = LC + t / LC;
        Bth[l][m] = (__fp16)0; Btl[l][m] = (__fp16)0;
    }
    __syncthreads();   // BAR6

    float* outb = out + (size_t)b * (4 * CTXM * LC);
#pragma unroll 1
    for (int i = 0; i < 4; i++) {
        int dt = wid + 8 * i;
        int d0 = dt * 16;
        int dq = d0 + l15;
        half8 qf0 = *(const half8*)&Qs[dq * 56 + kq];
        half8 qf1 = *(const half8*)&Qs[dq * 56 + 32 + kq];
        float xv[8];
#pragma unroll
        for (int e = 0; e < 8; e++) {
            int m = kq + e;
            int mc = (m < LC) ? m : 0;
            float vv = Vb[(size_t)mc * CTXM + d0 + l15];
            xv[e] = (m < LC) ? vv : 0.f;
        }
        half8 vt = cvt8(xv);

        f32x4 accA[2] = {{0.f,0.f,0.f,0.f},{0.f,0.f,0.f,0.f}};
        f32x4 accB[2] = {{0.f,0.f,0.f,0.f},{0.f,0.f,0.f,0.f}};
#pragma unroll
        for (int n2 = 0; n2 < 2; n2++) {
            int lS = n2 * 16 + l15; if (lS > LC - 1) lS = LC - 1;
            half8 s1h0 = *(const half8*)&S1h[lS][kq];
            half8 s1l0 = *(const half8*)&S1l[lS][kq];
            half8 s1h1 = *(const half8*)&S1h[lS][32 + kq];
            half8 s1l1 = *(const half8*)&S1l[lS][32 + kq];
            accA[n2] = __builtin_amdgcn_mfma_f32_16x16x32_f16(qf0, s1h0, accA[n2], 0, 0, 0);
            accA[n2] = __builtin_amdgcn_mfma_f32_16x16x32_f16(qf0, s1l0, accA[n2], 0, 0, 0);
            accA[n2] = __builtin_amdgcn_mfma_f32_16x16x32_f16(qf1, s1h1, accA[n2], 0, 0, 0);
            accA[n2] = __builtin_amdgcn_mfma_f32_16x16x32_f16(qf1, s1l1, accA[n2], 0, 0, 0);
            half8 bh = *(const half8*)&Bth[lS][kq];
            half8 bl = *(const half8*)&Btl[lS][kq];
            accB[n2] = __builtin_amdgcn_mfma_f32_16x16x32_f16(vt, bh, accB[n2], 0, 0, 0);
            accB[n2] = __builtin_amdgcn_mfma_f32_16x16x32_f16(vt, bl, accB[n2], 0, 0, 0);
        }

#pragma unroll
        for (int n2 = 0; n2 < 2; n2++) {
            int l = n2 * 16 + l15;
            if (l < LC) {
#pragma unroll
                for (int r = 0; r < 4; r++) {
                    int d = d0 + rq + r;
                    float vv = Vb[(size_t)l * CTXM + d];
                    float a  = accA[n2][r];
                    float bv = accB[n2][r];
                    size_t base = (size_t)d * LC + l;
                    outb[base]                 = vv;
                    outb[base + CTXM * LC]     = a;
                    outb[base + 2 * CTXM * LC] = vv * a;
                    outb[base + 3 * CTXM * LC] = vv * bv;
                }
            }
        }
    }
}

extern "C" void kernel_launch(void* const* d_in, const int* in_sizes, int n_in,
                              void* d_out, int out_size, void* d_ws, size_t ws_size,
                              hipStream_t stream) {
    const float* Vid   = (const float*)d_in[0];
    const float* Ques  = (const float*)d_in[1];
    const float* Vmask = (const float*)d_in[2];
    const float* Qmask = (const float*)d_in[3];
    const float* tv    = (const float*)d_in[4];
    const float* tg    = (const float*)d_in[5];
    const float* tb    = (const float*)d_in[6];
    const float* w4V   = (const float*)d_in[7];
    const float* w4Q   = (const float*)d_in[8];
    const float* w4mlu = (const float*)d_in[9];
    const float* bias  = (const float*)d_in[10];
    float* out = (float*)d_out;

    float* scale = (float*)d_ws;                         // 512 f
    float* V     = scale + 512;                          // 40960*512 f (84 MB)
    char*  Bp    = (char*)(V + (size_t)40960 * 512);     // 2 MB packed B (single term)

    scale_kernel<<<512, 256, 0, stream>>>(tv, tg, scale);
    bpack_kernel<<<512, 256, 0, stream>>>(tv, scale, Bp);
    gemm_kernel<<<640, 512, 0, stream>>>(Vid, Bp, tb, V);
    attn_kernel<<<B_, 512, 0, stream>>>(Ques, Vmask, Qmask, w4V, w4Q, w4mlu, bias, V, out);
}